// Round 6
// baseline (29.382 us; speedup 1.0000x reference)
//
#include <hip/hip_runtime.h>

// Batched histogram with position cutoff:
// token_count[b, v] = #{ s : s < last_token_index[b] and input_ids[b, s] == v }
// B=256, S=4096, V=128000. Output int32 (131 MB).
//
// Design (R6 = R5 with compile fix): 16-bit packed LDS bins, single pass,
// no global atomics, XCD-local row grouping + nontemporal output stores.
//   - Counts bounded by S=4096 < 2^16 -> 16-bit bins exact; packed atomic
//     atomicAdd(&lds[d>>1], 1 << ((d&1)*16)) can never carry across halves.
//   - grid = 1024 blocks; swizzled so the 4 part-blocks of each row land on
//     the SAME XCD (row fetched once into that XCD's L2, 3 subsequent hits).
//   - 1024 threads, 64 KB LDS -> 2 blocks/CU resident; one block's store
//     phase overlaps the other's zero/scatter.
//   - Output is write-once, never re-read -> nontemporal int4 stores (native
//     ext_vector_type for the builtin) keep it out of L2.
//   Global traffic: 131 MB streaming NT stores + ~5 MB reads. Floor ~20 us.

#define NB      256
#define SLEN    4096
#define VOC     128000
#define THREADS 1024
#define BLOCKS_PER_ROW 4
#define BINS    32000          // bins per block
#define WORDS   (BINS / 2)     // 16000 packed 32-bit words = 64 KB
#define NXCD    8

typedef int vint4 __attribute__((ext_vector_type(4)));

__global__ __launch_bounds__(THREADS) void fused_hist_kernel(
    const int* __restrict__ input_ids,        // (B, S)
    const int* __restrict__ last_token_index, // (B, 1)
    int* __restrict__ out)                    // (B, V)
{
    __shared__ int lds[WORDS];                // 64 KB

    // XCD-local row grouping: default dispatch round-robins blockIdx across
    // the 8 XCDs (block i -> XCD i&7). Map so each XCD owns 32 complete rows
    // (all 4 parts of a row on one XCD -> its L2 caches the row once).
    const int i    = blockIdx.x;              // 0..1023
    const int xcd  = i & (NXCD - 1);
    const int j    = i >> 3;                  // 0..127
    const int b    = xcd * (NB / NXCD) + (j >> 2);
    const int part = j & (BLOCKS_PER_ROW - 1);
    const int lo   = part * BINS;

    const int* __restrict__ row_in = input_ids + (size_t)b * SLEN;
    int* __restrict__ row_out      = out + (size_t)b * VOC + lo;

    const int L = last_token_index[b];        // valid: s < L

    // ---- Load this thread's 4 tokens (int4, coalesced); skip past cutoff ----
    const int s0 = threadIdx.x * 4;           // SLEN / THREADS == 4
    vint4 t = { 0x40000000, 0x40000000, 0x40000000, 0x40000000 }; // sentinel
    if (s0 < L) {
        t = *reinterpret_cast<const vint4*>(row_in + s0);
        if (s0 + 1 >= L) t.y = 0x40000000;
        if (s0 + 2 >= L) t.z = 0x40000000;
        if (s0 + 3 >= L) t.w = 0x40000000;
    }

    // ---- Phase 1: zero LDS (4000 int4) ----
    vint4 z = { 0, 0, 0, 0 };
    vint4* __restrict__ l4 = reinterpret_cast<vint4*>(lds);
    for (int k = threadIdx.x; k < WORDS / 4; k += THREADS) {
        l4[k] = z;
    }
    __syncthreads();

    // ---- Phase 2: packed 16-bit scatter into this block's bin range ----
    {
        const int tok[4] = { t.x, t.y, t.z, t.w };
#pragma unroll
        for (int k = 0; k < 4; ++k) {
            const unsigned d = (unsigned)(tok[k] - lo);
            if (d < (unsigned)BINS) {
                atomicAdd(&lds[d >> 1], 1 << ((d & 1) * 16));
            }
        }
    }
    __syncthreads();

    // ---- Phase 3: expand packed counts, nontemporal int4 stream to global ----
    const int2* __restrict__ src = reinterpret_cast<const int2*>(lds); // 8000 int2
    vint4* __restrict__ dst = reinterpret_cast<vint4*>(row_out);       // 8000 int4
    for (int k = threadIdx.x; k < BINS / 4; k += THREADS) {
        int2 w = src[k];
        vint4 o;
        o.x = w.x & 0xFFFF;
        o.y = (int)((unsigned)w.x >> 16);
        o.z = w.y & 0xFFFF;
        o.w = (int)((unsigned)w.y >> 16);
        __builtin_nontemporal_store(o, &dst[k]);
    }
}

extern "C" void kernel_launch(void* const* d_in, const int* in_sizes, int n_in,
                              void* d_out, int out_size, void* d_ws, size_t ws_size,
                              hipStream_t stream) {
    const int* input_ids        = (const int*)d_in[0];
    const int* last_token_index = (const int*)d_in[1];
    int* out = (int*)d_out;

    fused_hist_kernel<<<dim3(NB * BLOCKS_PER_ROW), dim3(THREADS), 0, stream>>>(
        input_ids, last_token_index, out);
}

// Round 7
// 23.891 us; speedup vs baseline: 1.2299x; 1.2299x over previous
//
#include <hip/hip_runtime.h>

// Batched histogram with position cutoff:
// token_count[b, v] = #{ s : s < last_token_index[b] and input_ids[b, s] == v }
// B=256, S=4096, V=128000. Output int32 (131 MB).
//
// Design (R7 = R4 + XCD swizzle ONLY; NT stores reverted — they regressed
// 24.2 -> 29.4 us, the nt path writes slower than L2 write-combine for
// fully-coalesced streams):
//   - 16-bit packed LDS bins (counts <= 4096 < 2^16, exact; packed atomic
//     can never carry across halves).
//   - grid = 1024 blocks; swizzled so the 4 part-blocks of each row land on
//     the SAME XCD (row fetched once into that XCD's L2, 3 subsequent hits).
//   - 1024 threads, 64 KB LDS -> 2 blocks/CU; store phase of one block
//     overlaps zero/scatter of the other.
//   Global traffic: 131 MB streaming stores + ~5 MB reads. Floor ~20 us.

#define NB      256
#define SLEN    4096
#define VOC     128000
#define THREADS 1024
#define BLOCKS_PER_ROW 4
#define BINS    32000          // bins per block
#define WORDS   (BINS / 2)     // 16000 packed 32-bit words = 64 KB
#define NXCD    8

typedef int vint4 __attribute__((ext_vector_type(4)));

__global__ __launch_bounds__(THREADS) void fused_hist_kernel(
    const int* __restrict__ input_ids,        // (B, S)
    const int* __restrict__ last_token_index, // (B, 1)
    int* __restrict__ out)                    // (B, V)
{
    __shared__ int lds[WORDS];                // 64 KB

    // XCD-local row grouping: default dispatch round-robins blockIdx across
    // the 8 XCDs (block i -> XCD i&7). Map so each XCD owns 32 complete rows.
    const int i    = blockIdx.x;              // 0..1023
    const int xcd  = i & (NXCD - 1);
    const int j    = i >> 3;                  // 0..127
    const int b    = xcd * (NB / NXCD) + (j >> 2);
    const int part = j & (BLOCKS_PER_ROW - 1);
    const int lo   = part * BINS;

    const int* __restrict__ row_in = input_ids + (size_t)b * SLEN;
    int* __restrict__ row_out      = out + (size_t)b * VOC + lo;

    const int L = last_token_index[b];        // valid: s < L

    // ---- Load this thread's 4 tokens (int4, coalesced); mask past cutoff ----
    const int s0 = threadIdx.x * 4;           // SLEN / THREADS == 4
    vint4 t = { 0x40000000, 0x40000000, 0x40000000, 0x40000000 }; // sentinel
    if (s0 < L) {
        t = *reinterpret_cast<const vint4*>(row_in + s0);
        if (s0 + 1 >= L) t.y = 0x40000000;
        if (s0 + 2 >= L) t.z = 0x40000000;
        if (s0 + 3 >= L) t.w = 0x40000000;
    }

    // ---- Phase 1: zero LDS (4000 int4) ----
    vint4 z = { 0, 0, 0, 0 };
    vint4* __restrict__ l4 = reinterpret_cast<vint4*>(lds);
    for (int k = threadIdx.x; k < WORDS / 4; k += THREADS) {
        l4[k] = z;
    }
    __syncthreads();

    // ---- Phase 2: packed 16-bit scatter into this block's bin range ----
    {
        const int tok[4] = { t.x, t.y, t.z, t.w };
#pragma unroll
        for (int k = 0; k < 4; ++k) {
            const unsigned d = (unsigned)(tok[k] - lo);
            if (d < (unsigned)BINS) {
                atomicAdd(&lds[d >> 1], 1 << ((d & 1) * 16));
            }
        }
    }
    __syncthreads();

    // ---- Phase 3: expand packed counts and stream to global (int4) ----
    const int2* __restrict__ src = reinterpret_cast<const int2*>(lds); // 8000 int2
    vint4* __restrict__ dst = reinterpret_cast<vint4*>(row_out);       // 8000 int4
    for (int k = threadIdx.x; k < BINS / 4; k += THREADS) {
        int2 w = src[k];
        vint4 o;
        o.x = w.x & 0xFFFF;
        o.y = (int)((unsigned)w.x >> 16);
        o.z = w.y & 0xFFFF;
        o.w = (int)((unsigned)w.y >> 16);
        dst[k] = o;
    }
}

extern "C" void kernel_launch(void* const* d_in, const int* in_sizes, int n_in,
                              void* d_out, int out_size, void* d_ws, size_t ws_size,
                              hipStream_t stream) {
    const int* input_ids        = (const int*)d_in[0];
    const int* last_token_index = (const int*)d_in[1];
    int* out = (int*)d_out;

    fused_hist_kernel<<<dim3(NB * BLOCKS_PER_ROW), dim3(THREADS), 0, stream>>>(
        input_ids, last_token_index, out);
}